// Round 7
// baseline (168.846 us; speedup 1.0000x reference)
//
#include <hip/hip_runtime.h>

// hybridloss: arcface CE (512x100000x128 bf16-MFMA GEMM + exp-sum softmax)
//           + TV loss + bin loss + sum|FFT2(k)| (1024x1024 radix-2 DIF, bit-reversed
//             order OK — final sum is permutation-invariant).
// R7: normW pass DELETED — W normalization fused into the GEMM A-stage. Each of 782
//     blocks loads its 64KB fp32 W o-tile once (51.2 MB total, the only W read),
//     row-norms via halfRedSum, converts bf16 into full-K-resident swizzled Ash,
//     then loops 4 b-tiles (Bsh chunked from L2-hot xh). Removes 25.6MB Wh write +
//     25.6MB Wh read + 12512 normW blocks. labexp recomputes IDENTICAL bf16 values
//     from fp32 W (same halfRedSum order + f2bf => bit-identical operands).
// Workspace layout (bytes), total 11,777,024 (ws is 256 MiB):
//   [0,2048)              coslab[512]
//   [2048,133120)         xh: 512x128 bf16
//   [133120,8521728)      fbuf: 1024x1024 float2
//   [8521728,11724800)    gpart[1564][512]  (782 o-tiles x 2 wave-halves)
//   [11724800,11757568)   g2[16][512]
//   [11757568,11773952)   tvpart[1024] float4
//   [11773952,11774976)   fftpart[256]
//   [11774976,11777024)   labexp[512]

typedef short bf16x8 __attribute__((ext_vector_type(8)));
typedef float f32x4 __attribute__((ext_vector_type(4)));
typedef unsigned short u16;
typedef unsigned int u32;

#define BATCH 512
#define DIM 128
#define OUTN 100000
#define NOBLK 782
#define NROW2 1564      // gpart rows
#define CHUNKS 16
#define CHSZ2 98        // 16*98 = 1568 >= 1564
#define SSCALE 32.0f
#define K2C 46.166241308446828f   // 32 * log2(e)
#define COSM 0.8775825618903728f
#define SINM 0.479425538604203f
#define THC (-0.8775825618903728f)
#define MMC 0.2397127693021015f

// stage1 role boundaries (blockIdx.x): fftrow | tvbin | xprep
#define S1_FFT 1024
#define S1_TV  2048
#define S1_NB  2176

// stage2: [0,256) fftcol (long blocks first); [256,256+782) gemm
#define S2_GEMM0 256
#define S2_NBLK  1038

__device__ inline u16 f2bf(float f) {
  union { float f; u32 u; } v; v.f = f;
  u32 r = v.u + 0x7FFFu + ((v.u >> 16) & 1u);   // round-to-nearest-even
  return (u16)(r >> 16);
}
__device__ inline float bflo(u32 u) { return __uint_as_float(u << 16); }
__device__ inline float bfhi(u32 u) { return __uint_as_float(u & 0xFFFF0000u); }

__device__ inline float waveRedSum(float v) {
#pragma unroll
  for (int off = 1; off < 64; off <<= 1) v += __shfl_xor(v, off, 64);
  return v;
}

__device__ inline float halfRedSum(float v) {   // reduce within each 32-lane half
#pragma unroll
  for (int off = 1; off < 32; off <<= 1) v += __shfl_xor(v, off, 64);
  return v;
}

// ---------------- stage 1: fftrow | tvbin | xprep ----------------
__global__ __launch_bounds__(256) void stage1_k(const float* __restrict__ x,
                                                const float* __restrict__ W,
                                                const int* __restrict__ label,
                                                const float* __restrict__ kimg,
                                                u32* __restrict__ xh,
                                                float* __restrict__ coslab,
                                                float4* __restrict__ tvpart,
                                                float2* __restrict__ fbuf) {
  __shared__ __align__(16) float smem[2064];
  int t = threadIdx.x;
  int bid = blockIdx.x;

  if (bid < S1_FFT) {
    // ---- row FFT: 1024-pt radix-2 DIF (bit-reversed out, fine) ----
    float* re = smem;
    float* im = smem + 1024;
    int r = bid;
#pragma unroll
    for (int i = 0; i < 4; i++) {
      int idx = i * 256 + t;
      re[idx] = kimg[r * 1024 + idx];
      im[idx] = 0.f;
    }
    __syncthreads();
    for (int lh = 9; lh >= 0; lh--) {
      int hlf = 1 << lh;
      float ang = -6.283185307179586f / (float)(hlf * 2);
#pragma unroll
      for (int i = 0; i < 2; i++) {
        int bf = i * 256 + t;
        int pos = bf & (hlf - 1);
        int g = bf >> lh;
        int i0 = (g << (lh + 1)) + pos;
        int i1 = i0 + hlf;
        float ur = re[i0], ui = im[i0], vr = re[i1], vi = im[i1];
        float s, c;
        __sincosf(ang * (float)pos, &s, &c);
        re[i0] = ur + vr; im[i0] = ui + vi;
        float dr = ur - vr, di = ui - vi;
        re[i1] = dr * c - di * s;
        im[i1] = dr * s + di * c;
      }
      __syncthreads();
    }
#pragma unroll
    for (int i = 0; i < 4; i++) {
      int idx = i * 256 + t;
      fbuf[(size_t)r * 1024 + idx] = make_float2(re[idx], im[idx]);
    }
  } else if (bid < S1_TV) {
    // ---- TV + bin loss, one image row per block ----
    int r = bid - S1_FFT;
    int idx = r * 1024 + t * 4;
    float4 v = *(const float4*)&kimg[idx];
    float bs = v.x * v.x + (v.x - 1.f) * (v.x - 1.f)
             + v.y * v.y + (v.y - 1.f) * (v.y - 1.f)
             + v.z * v.z + (v.z - 1.f) * (v.z - 1.f)
             + v.w * v.w + (v.w - 1.f) * (v.w - 1.f);
    float d0 = v.y - v.x, d1 = v.z - v.y, d2 = v.w - v.z;
    float wsm = d0 * d0 + d1 * d1 + d2 * d2;
    if (t < 255) { float e4 = kimg[idx + 4]; float d3 = e4 - v.w; wsm += d3 * d3; }
    float hs = 0.f;
    if (r < 1023) {
      float4 n = *(const float4*)&kimg[idx + 1024];
      float h0 = n.x - v.x, h1 = n.y - v.y, h2 = n.z - v.z, h3 = n.w - v.w;
      hs = h0 * h0 + h1 * h1 + h2 * h2 + h3 * h3;
    }
    hs = waveRedSum(hs); wsm = waveRedSum(wsm); bs = waveRedSum(bs);
    float (*red)[4] = (float(*)[4])smem;
    if ((t & 63) == 0) { int w = t >> 6; red[0][w] = hs; red[1][w] = wsm; red[2][w] = bs; }
    __syncthreads();
    if (t == 0)
      tvpart[r] = make_float4(red[0][0] + red[0][1] + red[0][2] + red[0][3],
                              red[1][0] + red[1][1] + red[1][2] + red[1][3],
                              red[2][0] + red[2][1] + red[2][2] + red[2][3], 0.f);
  } else {
    // ---- x normalize -> bf16 + cosine(x_b, W[label_b]) ----
    int b = (bid - S1_TV) * 4 + (t >> 6);
    int lane = t & 63;
    size_t xb = (size_t)b * DIM;
    float2 v = *(const float2*)&x[xb + lane * 2];
    int lab = label[b];
    size_t wb = (size_t)lab * DIM;
    float2 w = *(const float2*)&W[wb + lane * 2];
    float ss = waveRedSum(v.x * v.x + v.y * v.y);
    float d  = waveRedSum(v.x * w.x + v.y * w.y);
    float nw = waveRedSum(w.x * w.x + w.y * w.y);
    float inv = rsqrtf(ss);
    xh[b * 64 + lane] = (u32)f2bf(v.x * inv) | ((u32)f2bf(v.y * inv) << 16);
    if (lane == 0) coslab[b] = d * rsqrtf(ss * nw);
  }
}

// ---------------- stage 2: fftcol (first) | gemm (fused W-normalize) ----------------
__global__ __launch_bounds__(256, 3) void stage2_k(const float* __restrict__ W,
                                                   const u16* __restrict__ xh16,
                                                   float* __restrict__ gpart,
                                                   const float2* __restrict__ fbuf,
                                                   float* __restrict__ fftpart) {
  __shared__ __align__(16) char smem[49168];
  int t = threadIdx.x;
  int bid = blockIdx.x;

  if (bid >= S2_GEMM0) {
    // ---- GEMM role: 128(o) x 512(b), K=128; A normalized+resident in LDS ----
    int o = bid - S2_GEMM0;               // 0..781
    int o0 = o * 128;
    u16* Ash = (u16*)smem;                // 128 x 128 bf16, 16B-chunk XOR(row&15) (32 KB)
    u16* Bsh = (u16*)(smem + 32768);      // 128 x 64 bf16,  16B-chunk XOR(row&7)  (16 KB)
    int wv = t >> 6, lane = t & 63;
    int wo = (wv & 1) << 6, wbs = (wv >> 1) << 6;
    int m16 = lane & 15, q = lane >> 4;

    // Stage A: fp32 W -> row-norm -> bf16 (rows >= OUTN zeroed; no OOB reads).
#pragma unroll
    for (int it = 0; it < 16; it++) {
      int f = it * 256 + t;
      int rr = f >> 5, c = f & 31;        // 32 lanes per row (half-wave)
      int grow = o0 + rr;
      float4 v = make_float4(0.f, 0.f, 0.f, 0.f);
      if (grow < OUTN) v = *(const float4*)&W[(size_t)grow * DIM + c * 4];
      float ss = halfRedSum(v.x * v.x + v.y * v.y + v.z * v.z + v.w * v.w);
      float inv = (grow < OUTN) ? rsqrtf(ss) : 0.f;
      u32 lo = (u32)f2bf(v.x * inv) | ((u32)f2bf(v.y * inv) << 16);
      u32 hi = (u32)f2bf(v.z * inv) | ((u32)f2bf(v.w * inv) << 16);
      int dst = rr * 128 + (((c >> 1) ^ (rr & 15)) << 3) + ((c & 1) << 2);
      *(uint2*)&Ash[dst] = make_uint2(lo, hi);
    }
    __syncthreads();

    for (int bt = 0; bt < 4; bt++) {
      int b0 = bt * 128;
      f32x4 acc[4][4] = {};
#pragma unroll
      for (int kc = 0; kc < 2; kc++) {
        if (bt || kc) __syncthreads();    // WAR on Bsh vs previous reads
#pragma unroll
        for (int i2 = 0; i2 < 4; i2++) {
          int f = i2 * 256 + t;
          int rr = f >> 3, gg = f & 7;
          *(uint4*)&Bsh[rr * 64 + ((gg ^ (rr & 7)) << 3)] =
              *(const uint4*)&xh16[(size_t)(b0 + rr) * DIM + kc * 64 + gg * 8];
        }
        __syncthreads();
#pragma unroll
        for (int kkl = 0; kkl < 2; kkl++) {
          int kk = kc * 2 + kkl;
          bf16x8 af[4], bfr[4];
#pragma unroll
          for (int i = 0; i < 4; i++) {
            int row = wo + i * 16 + m16;
            af[i] = *(const bf16x8*)&Ash[row * 128 + ((((kk << 2) + q) ^ (row & 15)) << 3)];
          }
#pragma unroll
          for (int j = 0; j < 4; j++) {
            int row = wbs + j * 16 + m16;
            bfr[j] = *(const bf16x8*)&Bsh[row * 64 + ((((kkl << 2) + q) ^ (row & 7)) << 3)];
          }
#pragma unroll
          for (int i = 0; i < 4; i++)
#pragma unroll
            for (int j = 0; j < 4; j++)
              acc[i][j] = __builtin_amdgcn_mfma_f32_16x16x32_bf16(af[i], bfr[j], acc[i][j], 0, 0, 0);
        }
      }
      // Epilogue: unmasked exp2 sums (pad rows -> exp2(0)=1, subtracted in final).
#pragma unroll
      for (int j = 0; j < 4; j++) {
        float s = 0.f;
#pragma unroll
        for (int i = 0; i < 4; i++)
#pragma unroll
          for (int r = 0; r < 4; r++)
            s += exp2f(K2C * acc[i][j][r]);
        s += __shfl_xor(s, 16, 64);   // fold q-quadrants (same b, different o)
        s += __shfl_xor(s, 32, 64);
        if (q == 0)
          gpart[(size_t)(o * 2 + (wv & 1)) * 512 + b0 + wbs + j * 16 + m16] = s;
      }
    }
  } else {
    // ---- column FFT role (bids 0..255, long blocks first): 4 cols/block ----
    float2* arr = (float2*)smem;          // 4096 float2 = 32 KB
    float* red = (float*)(smem + 49152);
    int c0 = bid * 4;
#pragma unroll
    for (int i = 0; i < 16; i++) {
      int li = i * 256 + t;
      int rr = li >> 2, c = li & 3;
      arr[rr * 4 + c] = fbuf[(size_t)rr * 1024 + c0 + c];
    }
    __syncthreads();
    for (int lh = 9; lh >= 0; lh--) {
      int hlf = 1 << lh;
      float ang = -6.283185307179586f / (float)(hlf * 2);
#pragma unroll
      for (int i = 0; i < 8; i++) {
        int w = i * 256 + t;
        int c = w & 3, bf = w >> 2;
        int pos = bf & (hlf - 1), g2i = bf >> lh;
        int i0 = ((g2i << (lh + 1)) + pos) * 4 + c;
        int i1 = i0 + hlf * 4;
        float2 u = arr[i0], v = arr[i1];
        float s, cc;
        __sincosf(ang * (float)pos, &s, &cc);
        arr[i0] = make_float2(u.x + v.x, u.y + v.y);
        float dr = u.x - v.x, di = u.y - v.y;
        arr[i1] = make_float2(dr * cc - di * s, dr * s + di * cc);
      }
      __syncthreads();
    }
    float s = 0.f;
#pragma unroll
    for (int i = 0; i < 16; i++) {
      float2 v = arr[i * 256 + t];
      s += sqrtf(v.x * v.x + v.y * v.y);
    }
    s = waveRedSum(s);
    if ((t & 63) == 0) red[t >> 6] = s;
    __syncthreads();
    if (t == 0) fftpart[bid] = red[0] + red[1] + red[2] + red[3];
  }
}

// blocks 0..31: reduce gpart[1564][512] -> g2[16][512].
// blocks 32..95: labexp[b] = exp2(K2C * dot(bf16(x_b), bf16(W[lab]/||W[lab]||))),
//   half-wave per b, SAME halfRedSum order + f2bf as the gemm A-stage -> operands
//   bit-identical to what the MFMA summed for the label column.
__global__ __launch_bounds__(256) void gemmred_k(const float* __restrict__ gpart,
                                                 float* __restrict__ g2,
                                                 const u32* __restrict__ xh32,
                                                 const float* __restrict__ W,
                                                 const int* __restrict__ label,
                                                 float* __restrict__ labexp) {
  int t = threadIdx.x;
  int blk = blockIdx.x;
  if (blk < 32) {
    int chunk = blk >> 1, half = blk & 1;
    int b = half * 256 + t;
    int rBeg = chunk * CHSZ2;
    int rEnd = rBeg + CHSZ2; if (rEnd > NROW2) rEnd = NROW2;
    float s = 0.f;
    for (int r = rBeg; r < rEnd; r++) s += gpart[(size_t)r * 512 + b];
    g2[chunk * 512 + b] = s;
  } else {
    int b = (blk - 32) * 8 + (t >> 5);
    int c = t & 31;
    int lab = label[b];
    float4 v = *(const float4*)&W[(size_t)lab * DIM + c * 4];
    float ss = halfRedSum(v.x * v.x + v.y * v.y + v.z * v.z + v.w * v.w);
    float inv = rsqrtf(ss);
    u32 lo = (u32)f2bf(v.x * inv) | ((u32)f2bf(v.y * inv) << 16);
    u32 hi = (u32)f2bf(v.z * inv) | ((u32)f2bf(v.w * inv) << 16);
    uint2 xv = *(const uint2*)&xh32[b * 32 + c];
    float d = bflo(xv.x) * bflo(lo) + bfhi(xv.x) * bfhi(lo)
            + bflo(xv.y) * bflo(hi) + bfhi(xv.y) * bfhi(hi);
    d = halfRedSum(d);
    if (c == 0) labexp[b] = exp2f(K2C * d);
  }
}

__global__ __launch_bounds__(256) void final_k(const float* __restrict__ coslab,
                                               const float* __restrict__ g2,
                                               const float4* __restrict__ tvpart,
                                               const float* __restrict__ fftpart,
                                               const float* __restrict__ labexp,
                                               float* __restrict__ out) {
  int t = threadIdx.x;
  float arc = 0.f, hs = 0.f, wsm = 0.f, bs = 0.f, fs = 0.f;
#pragma unroll
  for (int i = 0; i < 2; i++) {
    int b = i * 256 + t;
    float se = 0.f;
#pragma unroll
    for (int c = 0; c < CHUNKS; c++) se += g2[c * 512 + b];
    se -= 96.0f;            // 100096-100000 zero rows contribute exp2(0)=1 each
    se -= labexp[b];        // remove bf16 label column
    float cl = coslab[b];
    float sine = sqrtf(fmaxf(0.f, 1.f - cl * cl));
    float phi = cl * COSM - sine * SINM;
    if (!(cl - THC > 0.f)) phi = cl - MMC;
    arc += __logf(se + exp2f(K2C * phi)) - SSCALE * phi;
  }
#pragma unroll
  for (int i = 0; i < 4; i++) {
    float4 p = tvpart[i * 256 + t];
    hs += p.x; wsm += p.y; bs += p.z;
  }
  fs = fftpart[t];
  arc = waveRedSum(arc); hs = waveRedSum(hs); wsm = waveRedSum(wsm);
  bs = waveRedSum(bs); fs = waveRedSum(fs);
  __shared__ float red[5][4];
  if ((t & 63) == 0) {
    int w = t >> 6;
    red[0][w] = arc; red[1][w] = hs; red[2][w] = wsm; red[3][w] = bs; red[4][w] = fs;
  }
  __syncthreads();
  if (t == 0) {
    float A = 0, H = 0, Wv = 0, Bv = 0, F = 0;
#pragma unroll
    for (int w = 0; w < 4; w++) {
      A += red[0][w]; H += red[1][w]; Wv += red[2][w]; Bv += red[3][w]; F += red[4][w];
    }
    float cnt = 1023.0f * 1024.0f;
    out[0] = A * (1.0f / 512.0f) - 2.0f * (H / cnt + Wv / cnt)
           + Bv * (1.0f / 1048576.0f) + F;
  }
}

extern "C" void kernel_launch(void* const* d_in, const int* in_sizes, int n_in,
                              void* d_out, int out_size, void* d_ws, size_t ws_size,
                              hipStream_t stream) {
  const float* x = (const float*)d_in[0];
  const int* label = (const int*)d_in[1];
  const float* kimg = (const float*)d_in[2];
  // d_in[3]=x0, d_in[4]=img — unused by the reference loss
  const float* W = (const float*)d_in[5];
  float* out = (float*)d_out;
  char* ws = (char*)d_ws;
  float*  coslab  = (float*)(ws + 0);
  u32*    xh      = (u32*)(ws + 2048);
  float2* fbuf    = (float2*)(ws + 133120);
  float*  gpart   = (float*)(ws + 8521728);    // 1564*512*4 = 3,203,072 B
  float*  g2      = (float*)(ws + 11724800);
  float4* tvpart  = (float4*)(ws + 11757568);
  float*  fftpart = (float*)(ws + 11773952);
  float*  labexp  = (float*)(ws + 11774976);

  hipLaunchKernelGGL(stage1_k, dim3(S1_NB), dim3(256), 0, stream,
                     x, W, label, kimg, xh, coslab, tvpart, fbuf);
  hipLaunchKernelGGL(stage2_k, dim3(S2_NBLK), dim3(256), 0, stream,
                     W, (const u16*)xh, gpart, fbuf, fftpart);
  hipLaunchKernelGGL(gemmred_k, dim3(96), dim3(256), 0, stream,
                     gpart, g2, xh, W, label, labexp);
  hipLaunchKernelGGL(final_k, dim3(1), dim3(256), 0, stream,
                     coslab, g2, tvpart, fftpart, labexp, out);
}